// Round 4
// baseline (292.089 us; speedup 1.0000x reference)
//
#include <hip/hip_runtime.h>

#define THRESH 1.0f
#define MIN_VMEM -1.0f

// IAF update: v += u; spike if v>=1; reset to 0 on spike; clamp to >= -1.
__device__ __forceinline__ float iaf_step(float& v, float u) {
    v += u;
    float s = (v >= THRESH) ? 1.f : 0.f;
    v = (s > 0.f) ? 0.f : v;
    v = fmaxf(v, MIN_VMEM);
    return s;
}

// ============================================================================
// K1: conv1 (2->8, 3x3, s2, p1) + IAF scan over T + 2x2 avgpool, fused.
// 800 blocks x 8 waves (512 thr). Block = (b, pooled row q); wave w -> co w.
//
// R3 post-mortem: splitting co across BLOCKS duplicated HBM fetch almost
// linearly (FETCH 159->318 MB when waves went 1600->3200) because the
// replica blocks are consecutive blockIdx.x -> round-robined onto DIFFERENT
// XCDs whose L2s don't share. This version gets occupancy (6400 waves =
// 6.25/SIMD) WITHOUT replication: the 10 input rows/frame (5 KB) are staged
// ONCE per block into double-buffered LDS (plain loads + ds_write, compiler-
// managed waits -> correct by construction) and consumed by all 8 waves.
// Logical fetch = 800 x 40 x 5 KB = 160 MB (vs R3's 640 MB logical).
// Latency hiding comes from TLP: ~3 blocks/CU with INDEPENDENT barriers.
//
// Per frame: threads 0..319 stage 10 rows (one float4 each, coalesced 512B
// rows); one __syncthreads per frame (double buffer). Wave w: lane l reads
// cols {2l,2l+1} of 10 rows from LDS (float2, 2-way bank alias = free),
// col 2l-1 via shfl_up, 36 FMA-triples -> 2 IAF states -> 2x2 pool via
// in-lane add + shfl_down, even lanes store 32-float pooled row.
// Boundary: top rows clamped in the staging address; q==0 zeroes rows 0/5
// in-register (conv reads input row -1 = zero pad). Arithmetic order per co
// identical to the verified R0 kernel (absmax 0.0).
// x: [25,40,2,128,128]  w1: [8,2,3,3]  -> ws1: [1000,8,32,32]
// ============================================================================
__global__ __launch_bounds__(512) void k1_conv1_iaf_pool(
        const float* __restrict__ x, const float* __restrict__ w1,
        float* __restrict__ ws1) {
    __shared__ float B[2][10][128];     // 10,240 B
    const int tid = threadIdx.x;
    const int lane = tid & 63;
    const int wv = tid >> 6;            // wave id = output channel
    const int q = blockIdx.x;           // pooled row 0..31
    const int b = blockIdx.y;
    const bool q0 = (q == 0);

    // this wave's 18 weights; wave-uniform addresses -> scalar loads
    float w[18];
    #pragma unroll
    for (int k = 0; k < 18; k++) w[k] = w1[wv * 18 + k];

    // staging role: threads 0..319 load one float4 of one row
    const int sr = tid >> 5;            // row 0..15 (valid < 10)
    const int sc = tid & 31;            // float4 index in row
    const int iy0 = 4 * q - 1;
    const float* xb = x + (size_t)(b * 40) * 32768;
    size_t goff = 0;
    if (sr < 10) {
        const int ci = sr / 5, rr = sr % 5;
        goff = (size_t)(ci * 16384 + max(iy0 + rr, 0) * 128 + sc * 4);
    }

    float vA = 0.f, vB = 0.f;

    // stage frame 0 into buffer 0
    if (sr < 10)
        *(float4*)&B[0][sr][4 * sc] = *(const float4*)(xb + goff);
    __syncthreads();

    for (int t = 0; t < 40; t++) {
        const int cur = t & 1;
        // stage frame t+1 into the spare buffer (overlaps with compute)
        if (t < 39 && sr < 10)
            *(float4*)&B[cur ^ 1][sr][4 * sc] =
                *(const float4*)(xb + (size_t)(t + 1) * 32768 + goff);
        // frame t: lane's 2 cols of 10 rows from LDS
        float2 F[10];
        #pragma unroll
        for (int m = 0; m < 10; m++)
            F[m] = *(const float2*)&B[cur][m][2 * lane];
        if (q0) { F[0] = make_float2(0.f, 0.f); F[5] = make_float2(0.f, 0.f); }
        // horizontal neighbor col 2l-1 via shuffle (lane 0 -> left pad)
        float xm[10];
        #pragma unroll
        for (int r = 0; r < 10; r++) {
            const float up = __shfl_up(F[r].y, 1);
            xm[r] = (lane == 0) ? 0.f : up;
        }
        // pre-activations: output rows A=2q (rows 0..2), B=2q+1 (rows 2..4)
        float preA = 0.f, preB = 0.f;
        #pragma unroll
        for (int ci = 0; ci < 2; ci++)
            #pragma unroll
            for (int ky = 0; ky < 3; ky++) {
                const int rA = ci * 5 + ky;
                const int rB = rA + 2;
                const float w0 = w[ci * 9 + ky * 3 + 0];
                const float w1v = w[ci * 9 + ky * 3 + 1];
                const float w2v = w[ci * 9 + ky * 3 + 2];
                preA += xm[rA] * w0 + F[rA].x * w1v + F[rA].y * w2v;
                preB += xm[rB] * w0 + F[rB].x * w1v + F[rB].y * w2v;
            }
        // IAF + 2x2 pool + dense stores (even lanes)
        float s = iaf_step(vA, preA) + iaf_step(vB, preB);
        s += __shfl_down(s, 1);
        if (!(lane & 1))
            ws1[((size_t)(b * 40 + t) * 8 + wv) * 1024 + q * 32 + (lane >> 1)]
                = s * 0.25f;
        __syncthreads();                // buf cur free for t+2's staging
    }
}

// ============================================================================
// K2a: conv2 (8->16, 3x3, s2, p1), one frame per block, 1000 blocks.
// Frame in zero-padded LDS [8][34][36]. Wave w -> c_out 4w..4w+3; lane ->
// 4 horizontally-adjacent outputs. Weights via readfirstlane -> s_load.
// ws1: [1000,8,32,32]  w2: [16,8,3,3] -> u2: [1000,16,16,16]
// ============================================================================
#define K2_CIS 1224             // 34 rows * 36 stride

__global__ __launch_bounds__(256) void k2a_conv2(
        const float* __restrict__ ws1, const float* __restrict__ w2,
        float* __restrict__ u2) {
    __shared__ float F[8 * K2_CIS];     // 39,168 B
    const int n = blockIdx.x;
    const int tid = threadIdx.x;

    for (int i = tid; i < 8 * K2_CIS; i += 256) F[i] = 0.f;
    __syncthreads();
    const float4* src = (const float4*)(ws1 + (size_t)n * 8192);
    #pragma unroll
    for (int k = 0; k < 8; k++) {
        const int i = tid + 256 * k;    // 0..2047
        const float4 q = src[i];
        const int ci = i >> 8;
        const int rr = i & 255;
        const int r = rr >> 3, c4 = rr & 7;
        float* d = &F[ci * K2_CIS + (r + 1) * 36 + 1 + 4 * c4];
        d[0] = q.x; d[1] = q.y; d[2] = q.z; d[3] = q.w;
    }
    __syncthreads();

    const int wv = tid >> 6;            // wave id -> c_out 4wv..4wv+3
    const int ln = tid & 63;
    const int oy = ln >> 2;             // 0..15
    const int ox4 = ln & 3;             // 4 outputs at ox = 4*ox4 + 0..3

    float acc[4][4];
    #pragma unroll
    for (int j = 0; j < 4; j++)
        #pragma unroll
        for (int k = 0; k < 4; k++) acc[j][k] = 0.f;

    #pragma unroll
    for (int ci = 0; ci < 8; ci++) {
        float q[3][9];
        const int base = ci * K2_CIS + (2 * oy) * 36 + 8 * ox4;
        #pragma unroll
        for (int ky = 0; ky < 3; ky++) {
            const float4 qa = *(const float4*)&F[base + ky * 36];
            const float4 qb = *(const float4*)&F[base + ky * 36 + 4];
            q[ky][0] = qa.x; q[ky][1] = qa.y; q[ky][2] = qa.z; q[ky][3] = qa.w;
            q[ky][4] = qb.x; q[ky][5] = qb.y; q[ky][6] = qb.z; q[ky][7] = qb.w;
            q[ky][8] = F[base + ky * 36 + 8];
        }
        #pragma unroll
        for (int j = 0; j < 4; j++) {
            const int co_u = __builtin_amdgcn_readfirstlane(4 * wv + j);
            const float* wb = w2 + co_u * 72 + ci * 9;  // uniform -> s_load
            float wm[9];
            #pragma unroll
            for (int m = 0; m < 9; m++) wm[m] = wb[m];
            #pragma unroll
            for (int k = 0; k < 4; k++)
                #pragma unroll
                for (int ky = 0; ky < 3; ky++)
                    #pragma unroll
                    for (int kx = 0; kx < 3; kx++)
                        acc[j][k] += q[ky][2 * k + kx] * wm[ky * 3 + kx];
        }
    }
    float* db = u2 + (size_t)n * 4096 + oy * 16 + 4 * ox4;
    #pragma unroll
    for (int j = 0; j < 4; j++) {
        const int co = 4 * wv + j;
        *(float4*)(db + co * 256) =
            make_float4(acc[j][0], acc[j][1], acc[j][2], acc[j][3]);
    }
}

// ============================================================================
// K2b: IAF scan over T + 2x2 avgpool, stage 2. 400 single-wave blocks.
// Batch-8 double-buffered register prefetch.
// u2: [1000,16,16,16] -> ws2: [1000,16,8,8]
// ============================================================================
__global__ __launch_bounds__(64) void k2b_scan(
        const float* __restrict__ u2, float* __restrict__ ws2) {
    const int id = blockIdx.x * 64 + threadIdx.x;   // 0..25599
    const int b = id >> 10;
    const int c = (id >> 6) & 15;
    const int pp = id & 63;
    const int py = pp >> 3, px = pp & 7;
    const float* base = u2 + (size_t)(b * 40) * 4096 + c * 256
                      + (2 * py) * 16 + 2 * px;
    float* ob = ws2 + (size_t)(b * 40) * 1024 + c * 64 + py * 8 + px;

    float v0 = 0.f, v1 = 0.f, v2 = 0.f, v3 = 0.f;
    float2 P[2][8][2];
    #pragma unroll
    for (int tt = 0; tt < 8; tt++) {
        const float* nb = base + (size_t)tt * 4096;
        P[0][tt][0] = *(const float2*)(nb);
        P[0][tt][1] = *(const float2*)(nb + 16);
    }
    #pragma unroll
    for (int bt = 0; bt < 5; bt++) {
        if (bt < 4) {
            #pragma unroll
            for (int tt = 0; tt < 8; tt++) {
                const float* nb = base + (size_t)(8 * (bt + 1) + tt) * 4096;
                P[(bt + 1) & 1][tt][0] = *(const float2*)(nb);
                P[(bt + 1) & 1][tt][1] = *(const float2*)(nb + 16);
            }
        }
        #pragma unroll
        for (int tt = 0; tt < 8; tt++) {
            const float2 b0 = P[bt & 1][tt][0];
            const float2 b1 = P[bt & 1][tt][1];
            const float s = iaf_step(v0, b0.x) + iaf_step(v1, b0.y)
                          + iaf_step(v2, b1.x) + iaf_step(v3, b1.y);
            ob[(size_t)(8 * bt + tt) * 1024] = s * 0.25f;
        }
    }
}

// ============================================================================
// K3: fc1  ws2:[1000,1024] @ w3[64,1024]^T -> ws3:[1000,64]
// 2 rows per block, 500 blocks (w3 served from L2/L3).
// ============================================================================
__global__ __launch_bounds__(256) void k3_fc1(
        const float* __restrict__ ws2, const float* __restrict__ w3,
        float* __restrict__ ws3) {
    __shared__ float rows[2048];
    const int n0 = blockIdx.x * 2;
    const int tid = threadIdx.x;
    const float4* s = (const float4*)(ws2 + (size_t)n0 * 1024);
    #pragma unroll
    for (int k = 0; k < 2; k++)
        ((float4*)rows)[tid + 256 * k] = s[tid + 256 * k];
    __syncthreads();
    const int o = tid >> 2, ko = tid & 3;
    const float4* wp = (const float4*)(w3 + (size_t)o * 1024 + ko * 256);
    const float4* r0 = (const float4*)(rows + ko * 256);
    const float4* r1 = (const float4*)(rows + 1024 + ko * 256);
    float a0 = 0.f, a1 = 0.f;
    #pragma unroll 8
    for (int j = 0; j < 64; j++) {
        const float4 wv = wp[j];
        const float4 q0 = r0[j], q1 = r1[j];
        a0 += q0.x * wv.x + q0.y * wv.y + q0.z * wv.z + q0.w * wv.w;
        a1 += q1.x * wv.x + q1.y * wv.y + q1.z * wv.z + q1.w * wv.w;
    }
    a0 += __shfl_xor(a0, 1); a0 += __shfl_xor(a0, 2);
    a1 += __shfl_xor(a1, 1); a1 += __shfl_xor(a1, 2);
    if (ko == 0) {
        ws3[(size_t)(n0 + 0) * 64 + o] = a0;
        ws3[(size_t)(n0 + 1) * 64 + o] = a1;
    }
}

// ============================================================================
// K4: IAF + fc2 (64->11) + IAF. 256-thread blocks: parallel stage of all
// 2560 inputs + w4, wave-0 runs the 40-step IAF1 scan wholly in LDS,
// phase B (440 dots) and phase C in parallel.
// ============================================================================
__global__ __launch_bounds__(256) void k4_iaf_fc2_iaf(
        const float* __restrict__ ws3, const float* __restrict__ w4,
        float* __restrict__ out) {
    __shared__ float sld[2560];
    __shared__ float pre[40 * 12];
    __shared__ float w4s[704];
    const int b = blockIdx.x, tid = threadIdx.x;

    const float4* src = (const float4*)(ws3 + (size_t)b * 2560);
    for (int i = tid; i < 640; i += 256) ((float4*)sld)[i] = src[i];
    for (int i = tid; i < 176; i += 256) ((float4*)w4s)[i] = ((const float4*)w4)[i];
    __syncthreads();
    if (tid < 64) {                     // wave 0: IAF1 scan in place
        float v1 = 0.f;
        #pragma unroll
        for (int t = 0; t < 40; t++)
            sld[t * 64 + tid] = iaf_step(v1, sld[t * 64 + tid]);
    }
    __syncthreads();
    for (int idx = tid; idx < 440; idx += 256) {
        const int t = idx % 40, o = idx / 40;
        const float4* spr = (const float4*)(sld + t * 64);
        const float4* wr = (const float4*)(w4s + o * 64);
        float acc = 0.f;
        #pragma unroll
        for (int qq = 0; qq < 16; qq++) {
            const float4 a = spr[qq], ww = wr[qq];
            acc += a.x * ww.x + a.y * ww.y + a.z * ww.z + a.w * ww.w;
        }
        pre[t * 12 + o] = acc;
    }
    __syncthreads();
    if (tid < 11) {
        float v2 = 0.f;
        for (int t = 0; t < 40; t++)
            out[(size_t)(b * 40 + t) * 11 + tid] = iaf_step(v2, pre[t * 12 + tid]);
    }
}

extern "C" void kernel_launch(void* const* d_in, const int* in_sizes, int n_in,
                              void* d_out, int out_size, void* d_ws, size_t ws_size,
                              hipStream_t stream) {
    const float* x  = (const float*)d_in[0];   // [25,40,2,128,128]
    const float* w1 = (const float*)d_in[1];   // [8,2,3,3]
    const float* w2 = (const float*)d_in[2];   // [16,8,3,3]
    const float* w3 = (const float*)d_in[3];   // [64,1024]
    const float* w4 = (const float*)d_in[4];   // [11,64]
    float* out = (float*)d_out;                // [25,40,11]

    float* ws1 = (float*)d_ws;                 // 1000*8*32*32 = 8,192,000 f
    float* ws2 = ws1 + 8192000;                // 1000*16*8*8  = 1,024,000 f
    float* ws3 = ws2 + 1024000;                // 1000*64      =    64,000 f
    // u2 (16.4 MB): prefer d_ws (keeps inputs pristine -> no harness restore
    // traffic in the timed path); fall back to x's buffer (x dead after K1)
    // only if the workspace is too small. Total need = 53,504,000 B.
    float* u2;
    if (ws_size >= (size_t)(8192000 + 1024000 + 64000 + 4096000) * 4)
        u2 = ws3 + 64000;
    else
        u2 = (float*)d_in[0];

    k1_conv1_iaf_pool<<<dim3(32, 25), 512, 0, stream>>>(x, w1, ws1);
    k2a_conv2<<<1000, 256, 0, stream>>>(ws1, w2, u2);
    k2b_scan<<<400, 64, 0, stream>>>(u2, ws2);
    k3_fc1<<<500, 256, 0, stream>>>(ws2, w3, ws3);
    k4_iaf_fc2_iaf<<<25, 256, 0, stream>>>(ws3, w4, out);
}

// Round 5
// 271.908 us; speedup vs baseline: 1.0742x; 1.0742x over previous
//
#include <hip/hip_runtime.h>

#define THRESH 1.0f
#define MIN_VMEM -1.0f

// IAF update: v += u; spike if v>=1; reset to 0 on spike; clamp to >= -1.
__device__ __forceinline__ float iaf_step(float& v, float u) {
    v += u;
    float s = (v >= THRESH) ? 1.f : 0.f;
    v = (s > 0.f) ? 0.f : v;
    v = fmaxf(v, MIN_VMEM);
    return s;
}

// ============================================================================
// K1: conv1 (2->8, 3x3, s2, p1) + IAF scan over T + 2x2 avgpool, fused.
// 3200 single-wave blocks (1D grid, XCD-swizzled). Wave = (b, q, g -> co 2g+j).
//
// R0/R3/R4 triangulation: R3 (this exact body, naive 2D grid) delivered
// 640 MB logical at a COMBINED L2+HBM rate of 6.3 TB/s -> it was memory-
// throughput-bound on its own 4x replica traffic (FETCH 318 MB: the 4
// co-replica blocks of each (b,q) are consecutive blockIdx -> round-robin
// onto DIFFERENT XCDs, whose L2s don't share). R4 deduped via 8-wave LDS
// blocks but its lockstep barriers throttled memory to 1.5 TB/s (109 us).
// THIS version keeps R3's barrier-free structure and dedupes in L2 via an
// XCD-aware swizzle: unit u=(b,q) 0..799, replica g 0..3 maps to linear
//   S = (u/8)*32 + g*8 + (u%8)
// so all 4 replicas of u satisfy S%8 == u%8 -> same XCD (round-robin
// dispatch), within a 24-block dispatch window -> 3 of 4 frame reads hit
// that XCD's L2. Per-XCD per-step working set: 100 units x 5 KB = 500 KB
// << 4 MB L2. Expected FETCH ~ 165 MB (1.25x row-overlap floor; adjacent-q
// overlap still crosses XCDs). If the XCD mapping differs, perf falls back
// to R3 -- correctness unaffected.
// #pragma unroll 2 on the t-loop: batches the 10 loads of steps t,t+1 ->
// halves exposed latency (IAF dependency only serializes the VALU tail).
//
// Lane l owns input cols {2l, 2l+1}; col 2l-1 via shfl_up. Per step:
// 10 float2 loads (coalesced 512B rows), 72 FMA, 4 IAF states, 2x2 pool via
// in-lane add + shfl_down, even lanes store 2 dwords. Arithmetic order
// IDENTICAL to the verified R0/R3 kernels (absmax 0.0).
// x: [25,40,2,128,128]  w1: [8,2,3,3]  -> ws1: [1000,8,32,32]
// ============================================================================
__global__ __launch_bounds__(64) void k1_conv1_iaf_pool(
        const float* __restrict__ x, const float* __restrict__ w1,
        float* __restrict__ ws1) {
    const int lane = threadIdx.x;
    // de-swizzle: S -> (unit u, replica g)
    const int S = blockIdx.x;           // 0..3199
    const int chunk = S >> 5;           // 0..99
    const int r = S & 31;
    const int g = r >> 3;               // co = 2g + j, j in {0,1}
    const int u = chunk * 8 + (r & 7);  // 0..799
    const int b = u >> 5;               // batch 0..24
    const int q = u & 31;               // pooled row 0..31
    const bool q0 = (q == 0);

    // 2 co x 18 weights; wave-uniform addresses -> scalar loads
    float w[2][18];
    #pragma unroll
    for (int j = 0; j < 2; j++)
        #pragma unroll
        for (int k = 0; k < 18; k++)
            w[j][k] = w1[(2 * g + j) * 18 + k];

    // row offsets (floats) of the 10 rows (5 per ci), clamped at the top;
    // lane offset folded into the base pointer
    const int iy0 = 4 * q - 1;
    int roff[10];
    #pragma unroll
    for (int r2 = 0; r2 < 10; r2++) {
        const int ci = r2 / 5, rr = r2 % 5;
        roff[r2] = ci * 16384 + max(iy0 + rr, 0) * 128;
    }
    const float* xfl = x + (size_t)(b * 40) * 32768 + lane * 2;

    float vA[2], vB[2];
    #pragma unroll
    for (int j = 0; j < 2; j++) { vA[j] = 0.f; vB[j] = 0.f; }

    #pragma unroll 2
    for (int t = 0; t < 40; t++) {
        const float* xt = xfl + (size_t)t * 32768;
        // frame t: lane's 2 cols of 10 rows -> 10 coalesced 512B row loads
        float2 F[10];
        #pragma unroll
        for (int m = 0; m < 10; m++)
            F[m] = *(const float2*)(xt + roff[m]);
        if (q0) { F[0] = make_float2(0.f, 0.f); F[5] = make_float2(0.f, 0.f); }
        // horizontal neighbor col 2l-1 via shuffle (lane 0 -> left pad)
        float xm[10];
        #pragma unroll
        for (int r2 = 0; r2 < 10; r2++) {
            const float up = __shfl_up(F[r2].y, 1);
            xm[r2] = (lane == 0) ? 0.f : up;
        }
        // pre-activations: output rows A=2q (rows 0..2), B=2q+1 (rows 2..4)
        float preA[2], preB[2];
        #pragma unroll
        for (int j = 0; j < 2; j++) { preA[j] = 0.f; preB[j] = 0.f; }
        #pragma unroll
        for (int ci = 0; ci < 2; ci++)
            #pragma unroll
            for (int ky = 0; ky < 3; ky++) {
                const int rA = ci * 5 + ky;
                const int rB = rA + 2;
                #pragma unroll
                for (int j = 0; j < 2; j++) {
                    const float w0 = w[j][ci * 9 + ky * 3 + 0];
                    const float w1v = w[j][ci * 9 + ky * 3 + 1];
                    const float w2v = w[j][ci * 9 + ky * 3 + 2];
                    preA[j] += xm[rA] * w0 + F[rA].x * w1v + F[rA].y * w2v;
                    preB[j] += xm[rB] * w0 + F[rB].x * w1v + F[rB].y * w2v;
                }
            }
        // IAF + 2x2 pool + dense stores (even lanes)
        const size_t nbase = ((size_t)(b * 40 + t) * 8 + 2 * g) * 1024 + q * 32;
        #pragma unroll
        for (int j = 0; j < 2; j++) {
            float s = iaf_step(vA[j], preA[j]) + iaf_step(vB[j], preB[j]);
            s += __shfl_down(s, 1);
            if (!(lane & 1))
                ws1[nbase + (size_t)j * 1024 + (lane >> 1)] = s * 0.25f;
        }
    }
}

// ============================================================================
// K2a: conv2 (8->16, 3x3, s2, p1), one frame per block, 1000 blocks.
// Frame in zero-padded LDS [8][34][36]. Wave w -> c_out 4w..4w+3; lane ->
// 4 horizontally-adjacent outputs. Weights via readfirstlane -> s_load.
// ws1: [1000,8,32,32]  w2: [16,8,3,3] -> u2: [1000,16,16,16]
// ============================================================================
#define K2_CIS 1224             // 34 rows * 36 stride

__global__ __launch_bounds__(256) void k2a_conv2(
        const float* __restrict__ ws1, const float* __restrict__ w2,
        float* __restrict__ u2) {
    __shared__ float F[8 * K2_CIS];     // 39,168 B
    const int n = blockIdx.x;
    const int tid = threadIdx.x;

    for (int i = tid; i < 8 * K2_CIS; i += 256) F[i] = 0.f;
    __syncthreads();
    const float4* src = (const float4*)(ws1 + (size_t)n * 8192);
    #pragma unroll
    for (int k = 0; k < 8; k++) {
        const int i = tid + 256 * k;    // 0..2047
        const float4 q = src[i];
        const int ci = i >> 8;
        const int rr = i & 255;
        const int r = rr >> 3, c4 = rr & 7;
        float* d = &F[ci * K2_CIS + (r + 1) * 36 + 1 + 4 * c4];
        d[0] = q.x; d[1] = q.y; d[2] = q.z; d[3] = q.w;
    }
    __syncthreads();

    const int wv = tid >> 6;            // wave id -> c_out 4wv..4wv+3
    const int ln = tid & 63;
    const int oy = ln >> 2;             // 0..15
    const int ox4 = ln & 3;             // 4 outputs at ox = 4*ox4 + 0..3

    float acc[4][4];
    #pragma unroll
    for (int j = 0; j < 4; j++)
        #pragma unroll
        for (int k = 0; k < 4; k++) acc[j][k] = 0.f;

    #pragma unroll
    for (int ci = 0; ci < 8; ci++) {
        float q[3][9];
        const int base = ci * K2_CIS + (2 * oy) * 36 + 8 * ox4;
        #pragma unroll
        for (int ky = 0; ky < 3; ky++) {
            const float4 qa = *(const float4*)&F[base + ky * 36];
            const float4 qb = *(const float4*)&F[base + ky * 36 + 4];
            q[ky][0] = qa.x; q[ky][1] = qa.y; q[ky][2] = qa.z; q[ky][3] = qa.w;
            q[ky][4] = qb.x; q[ky][5] = qb.y; q[ky][6] = qb.z; q[ky][7] = qb.w;
            q[ky][8] = F[base + ky * 36 + 8];
        }
        #pragma unroll
        for (int j = 0; j < 4; j++) {
            const int co_u = __builtin_amdgcn_readfirstlane(4 * wv + j);
            const float* wb = w2 + co_u * 72 + ci * 9;  // uniform -> s_load
            float wm[9];
            #pragma unroll
            for (int m = 0; m < 9; m++) wm[m] = wb[m];
            #pragma unroll
            for (int k = 0; k < 4; k++)
                #pragma unroll
                for (int ky = 0; ky < 3; ky++)
                    #pragma unroll
                    for (int kx = 0; kx < 3; kx++)
                        acc[j][k] += q[ky][2 * k + kx] * wm[ky * 3 + kx];
        }
    }
    float* db = u2 + (size_t)n * 4096 + oy * 16 + 4 * ox4;
    #pragma unroll
    for (int j = 0; j < 4; j++) {
        const int co = 4 * wv + j;
        *(float4*)(db + co * 256) =
            make_float4(acc[j][0], acc[j][1], acc[j][2], acc[j][3]);
    }
}

// ============================================================================
// K2b: IAF scan over T + 2x2 avgpool, stage 2. 400 single-wave blocks.
// Batch-8 double-buffered register prefetch.
// u2: [1000,16,16,16] -> ws2: [1000,16,8,8]
// ============================================================================
__global__ __launch_bounds__(64) void k2b_scan(
        const float* __restrict__ u2, float* __restrict__ ws2) {
    const int id = blockIdx.x * 64 + threadIdx.x;   // 0..25599
    const int b = id >> 10;
    const int c = (id >> 6) & 15;
    const int pp = id & 63;
    const int py = pp >> 3, px = pp & 7;
    const float* base = u2 + (size_t)(b * 40) * 4096 + c * 256
                      + (2 * py) * 16 + 2 * px;
    float* ob = ws2 + (size_t)(b * 40) * 1024 + c * 64 + py * 8 + px;

    float v0 = 0.f, v1 = 0.f, v2 = 0.f, v3 = 0.f;
    float2 P[2][8][2];
    #pragma unroll
    for (int tt = 0; tt < 8; tt++) {
        const float* nb = base + (size_t)tt * 4096;
        P[0][tt][0] = *(const float2*)(nb);
        P[0][tt][1] = *(const float2*)(nb + 16);
    }
    #pragma unroll
    for (int bt = 0; bt < 5; bt++) {
        if (bt < 4) {
            #pragma unroll
            for (int tt = 0; tt < 8; tt++) {
                const float* nb = base + (size_t)(8 * (bt + 1) + tt) * 4096;
                P[(bt + 1) & 1][tt][0] = *(const float2*)(nb);
                P[(bt + 1) & 1][tt][1] = *(const float2*)(nb + 16);
            }
        }
        #pragma unroll
        for (int tt = 0; tt < 8; tt++) {
            const float2 b0 = P[bt & 1][tt][0];
            const float2 b1 = P[bt & 1][tt][1];
            const float s = iaf_step(v0, b0.x) + iaf_step(v1, b0.y)
                          + iaf_step(v2, b1.x) + iaf_step(v3, b1.y);
            ob[(size_t)(8 * bt + tt) * 1024] = s * 0.25f;
        }
    }
}

// ============================================================================
// K3: fc1  ws2:[1000,1024] @ w3[64,1024]^T -> ws3:[1000,64]
// 2 rows per block, 500 blocks (w3 served from L2/L3).
// ============================================================================
__global__ __launch_bounds__(256) void k3_fc1(
        const float* __restrict__ ws2, const float* __restrict__ w3,
        float* __restrict__ ws3) {
    __shared__ float rows[2048];
    const int n0 = blockIdx.x * 2;
    const int tid = threadIdx.x;
    const float4* s = (const float4*)(ws2 + (size_t)n0 * 1024);
    #pragma unroll
    for (int k = 0; k < 2; k++)
        ((float4*)rows)[tid + 256 * k] = s[tid + 256 * k];
    __syncthreads();
    const int o = tid >> 2, ko = tid & 3;
    const float4* wp = (const float4*)(w3 + (size_t)o * 1024 + ko * 256);
    const float4* r0 = (const float4*)(rows + ko * 256);
    const float4* r1 = (const float4*)(rows + 1024 + ko * 256);
    float a0 = 0.f, a1 = 0.f;
    #pragma unroll 8
    for (int j = 0; j < 64; j++) {
        const float4 wv = wp[j];
        const float4 q0 = r0[j], q1 = r1[j];
        a0 += q0.x * wv.x + q0.y * wv.y + q0.z * wv.z + q0.w * wv.w;
        a1 += q1.x * wv.x + q1.y * wv.y + q1.z * wv.z + q1.w * wv.w;
    }
    a0 += __shfl_xor(a0, 1); a0 += __shfl_xor(a0, 2);
    a1 += __shfl_xor(a1, 1); a1 += __shfl_xor(a1, 2);
    if (ko == 0) {
        ws3[(size_t)(n0 + 0) * 64 + o] = a0;
        ws3[(size_t)(n0 + 1) * 64 + o] = a1;
    }
}

// ============================================================================
// K4: IAF + fc2 (64->11) + IAF. 256-thread blocks: parallel stage of all
// 2560 inputs + w4, wave-0 runs the 40-step IAF1 scan wholly in LDS,
// phase B (440 dots) and phase C in parallel.
// ============================================================================
__global__ __launch_bounds__(256) void k4_iaf_fc2_iaf(
        const float* __restrict__ ws3, const float* __restrict__ w4,
        float* __restrict__ out) {
    __shared__ float sld[2560];
    __shared__ float pre[40 * 12];
    __shared__ float w4s[704];
    const int b = blockIdx.x, tid = threadIdx.x;

    const float4* src = (const float4*)(ws3 + (size_t)b * 2560);
    for (int i = tid; i < 640; i += 256) ((float4*)sld)[i] = src[i];
    for (int i = tid; i < 176; i += 256) ((float4*)w4s)[i] = ((const float4*)w4)[i];
    __syncthreads();
    if (tid < 64) {                     // wave 0: IAF1 scan in place
        float v1 = 0.f;
        #pragma unroll
        for (int t = 0; t < 40; t++)
            sld[t * 64 + tid] = iaf_step(v1, sld[t * 64 + tid]);
    }
    __syncthreads();
    for (int idx = tid; idx < 440; idx += 256) {
        const int t = idx % 40, o = idx / 40;
        const float4* spr = (const float4*)(sld + t * 64);
        const float4* wr = (const float4*)(w4s + o * 64);
        float acc = 0.f;
        #pragma unroll
        for (int qq = 0; qq < 16; qq++) {
            const float4 a = spr[qq], ww = wr[qq];
            acc += a.x * ww.x + a.y * ww.y + a.z * ww.z + a.w * ww.w;
        }
        pre[t * 12 + o] = acc;
    }
    __syncthreads();
    if (tid < 11) {
        float v2 = 0.f;
        for (int t = 0; t < 40; t++)
            out[(size_t)(b * 40 + t) * 11 + tid] = iaf_step(v2, pre[t * 12 + tid]);
    }
}

extern "C" void kernel_launch(void* const* d_in, const int* in_sizes, int n_in,
                              void* d_out, int out_size, void* d_ws, size_t ws_size,
                              hipStream_t stream) {
    const float* x  = (const float*)d_in[0];   // [25,40,2,128,128]
    const float* w1 = (const float*)d_in[1];   // [8,2,3,3]
    const float* w2 = (const float*)d_in[2];   // [16,8,3,3]
    const float* w3 = (const float*)d_in[3];   // [64,1024]
    const float* w4 = (const float*)d_in[4];   // [11,64]
    float* out = (float*)d_out;                // [25,40,11]

    float* ws1 = (float*)d_ws;                 // 1000*8*32*32 = 8,192,000 f
    float* ws2 = ws1 + 8192000;                // 1000*16*8*8  = 1,024,000 f
    float* ws3 = ws2 + 1024000;                // 1000*64      =    64,000 f
    // u2 (16.4 MB): prefer d_ws (keeps inputs pristine); fall back to x's
    // buffer (x dead after K1) only if the workspace is too small.
    float* u2;
    if (ws_size >= (size_t)(8192000 + 1024000 + 64000 + 4096000) * 4)
        u2 = ws3 + 64000;
    else
        u2 = (float*)d_in[0];

    k1_conv1_iaf_pool<<<3200, 64, 0, stream>>>(x, w1, ws1);
    k2a_conv2<<<1000, 256, 0, stream>>>(ws1, w2, u2);
    k2b_scan<<<400, 64, 0, stream>>>(u2, ws2);
    k3_fc1<<<500, 256, 0, stream>>>(ws2, w3, ws3);
    k4_iaf_fc2_iaf<<<25, 256, 0, stream>>>(ws3, w4, out);
}

// Round 6
// 270.827 us; speedup vs baseline: 1.0785x; 1.0040x over previous
//
#include <hip/hip_runtime.h>

#define THRESH 1.0f
#define MIN_VMEM -1.0f

// IAF update: v += u; spike if v>=1; reset to 0 on spike; clamp to >= -1.
__device__ __forceinline__ float iaf_step(float& v, float u) {
    v += u;
    float s = (v >= THRESH) ? 1.f : 0.f;
    v = (s > 0.f) ? 0.f : v;
    v = fmaxf(v, MIN_VMEM);
    return s;
}

// ============================================================================
// K1: conv1 (2->8, 3x3, s2, p1) + IAF scan over T + 2x2 avgpool, fused.
// 3200 single-wave blocks (1D grid, XCD-swizzled; R5's swizzle VERIFIED:
// FETCH 318->79.5 MB). Wave = (b, q, g -> co 2g+j).
//
// R5 post-mortem: step time still ~5.2K cyc with memory idle (1.3 TB/s) and
// VALUBusy 37% -> pure per-wave load latency. VGPR=36 proved the compiler
// collapsed `#pragma unroll 2` back into a single-buffer loop (loads ->
// vmcnt(0) -> compute every step, ~600-800 cyc L3 latency exposed). THIS
// version makes the double-buffer EXPLICIT in registers: distinct FA/FB
// (10 float2 each), refill of FA (frame t+2) textually after compute(t),
// frame index clamped (min(.,39)) instead of guarded by a branch so the
// 20-iter loop body is ONE basic block (branches would fence the scheduler
// and the refill would lose its aging). The compiler tracks plain loads
// precisely and emits counted vmcnt(N) for the one-step-aged group (the R1
// failure was LDS-DMA aliasing, the R2 failure was asm invisibility --
// neither applies to plain register loads).
//
// Lane l owns input cols {2l, 2l+1}; col 2l-1 via shfl_up. Per step:
// 10 float2 loads (coalesced 512B rows), 72 FMA, 4 IAF states, 2x2 pool via
// in-lane add + shfl_down, even lanes store 2 dwords. Arithmetic order per
// step IDENTICAL to the verified R0/R3/R5 kernels (absmax 0.0).
// x: [25,40,2,128,128]  w1: [8,2,3,3]  -> ws1: [1000,8,32,32]
// ============================================================================
__device__ __forceinline__ void k1_compute(
        float2 (&F)[10], const bool q0, const int lane,
        const float (&w)[2][18], float (&vA)[2], float (&vB)[2],
        float* __restrict__ ws1, const size_t nbase) {
    if (q0) { F[0] = make_float2(0.f, 0.f); F[5] = make_float2(0.f, 0.f); }
    // horizontal neighbor col 2l-1 via shuffle (lane 0 -> left pad)
    float xm[10];
    #pragma unroll
    for (int r = 0; r < 10; r++) {
        const float up = __shfl_up(F[r].y, 1);
        xm[r] = (lane == 0) ? 0.f : up;
    }
    // pre-activations: output rows A=2q (rows 0..2), B=2q+1 (rows 2..4)
    float preA[2], preB[2];
    #pragma unroll
    for (int j = 0; j < 2; j++) { preA[j] = 0.f; preB[j] = 0.f; }
    #pragma unroll
    for (int ci = 0; ci < 2; ci++)
        #pragma unroll
        for (int ky = 0; ky < 3; ky++) {
            const int rA = ci * 5 + ky;
            const int rB = rA + 2;
            #pragma unroll
            for (int j = 0; j < 2; j++) {
                const float w0 = w[j][ci * 9 + ky * 3 + 0];
                const float w1v = w[j][ci * 9 + ky * 3 + 1];
                const float w2v = w[j][ci * 9 + ky * 3 + 2];
                preA[j] += xm[rA] * w0 + F[rA].x * w1v + F[rA].y * w2v;
                preB[j] += xm[rB] * w0 + F[rB].x * w1v + F[rB].y * w2v;
            }
        }
    // IAF + 2x2 pool + dense stores (even lanes)
    #pragma unroll
    for (int j = 0; j < 2; j++) {
        float s = iaf_step(vA[j], preA[j]) + iaf_step(vB[j], preB[j]);
        s += __shfl_down(s, 1);
        if (!(lane & 1))
            ws1[nbase + (size_t)j * 1024 + (lane >> 1)] = s * 0.25f;
    }
}

__global__ __launch_bounds__(64) void k1_conv1_iaf_pool(
        const float* __restrict__ x, const float* __restrict__ w1,
        float* __restrict__ ws1) {
    const int lane = threadIdx.x;
    // de-swizzle: S -> (unit u, replica g); all 4 replicas of u share S%8
    // -> same XCD L2 (verified: FETCH 318 -> 79.5 MB)
    const int S = blockIdx.x;           // 0..3199
    const int chunk = S >> 5;           // 0..99
    const int r = S & 31;
    const int g = r >> 3;               // co = 2g + j, j in {0,1}
    const int u = chunk * 8 + (r & 7);  // 0..799
    const int b = u >> 5;               // batch 0..24
    const int q = u & 31;               // pooled row 0..31
    const bool q0 = (q == 0);

    // 2 co x 18 weights; wave-uniform addresses -> scalar loads
    float w[2][18];
    #pragma unroll
    for (int j = 0; j < 2; j++)
        #pragma unroll
        for (int k = 0; k < 18; k++)
            w[j][k] = w1[(2 * g + j) * 18 + k];

    // row offsets (floats) of the 10 rows (5 per ci), clamped at the top
    const int iy0 = 4 * q - 1;
    int roff[10];
    #pragma unroll
    for (int r2 = 0; r2 < 10; r2++) {
        const int ci = r2 / 5, rr = r2 % 5;
        roff[r2] = ci * 16384 + max(iy0 + rr, 0) * 128;
    }
    const float* xfl = x + (size_t)(b * 40) * 32768 + lane * 2;

    float vA[2], vB[2];
    #pragma unroll
    for (int j = 0; j < 2; j++) { vA[j] = 0.f; vB[j] = 0.f; }

    const size_t obase = ((size_t)(b * 40) * 8 + 2 * g) * 1024 + q * 32;

    // prologue: frames 0 (FA) and 1 (FB)
    float2 FA[10], FB[10];
    #pragma unroll
    for (int m = 0; m < 10; m++)
        FA[m] = *(const float2*)(xfl + roff[m]);
    #pragma unroll
    for (int m = 0; m < 10; m++)
        FB[m] = *(const float2*)(xfl + (size_t)32768 + roff[m]);

    for (int tt = 0; tt < 20; tt++) {
        const int t0 = 2 * tt;
        // step t0 from FA (waits only on FA's group, issued one step ago)
        k1_compute(FA, q0, lane, w, vA, vB, ws1, obase + (size_t)t0 * 8192);
        // refill FA <- frame t0+2 (clamped: iter 19 reloads frame 39,
        // harmless + keeps the body branchless = one BB for the scheduler)
        {
            const float* xn = xfl + (size_t)min(t0 + 2, 39) * 32768;
            #pragma unroll
            for (int m = 0; m < 10; m++)
                FA[m] = *(const float2*)(xn + roff[m]);
        }
        // step t0+1 from FB
        k1_compute(FB, q0, lane, w, vA, vB, ws1,
                   obase + (size_t)(t0 + 1) * 8192);
        // refill FB <- frame t0+3 (clamped)
        {
            const float* xn = xfl + (size_t)min(t0 + 3, 39) * 32768;
            #pragma unroll
            for (int m = 0; m < 10; m++)
                FB[m] = *(const float2*)(xn + roff[m]);
        }
    }
}

// ============================================================================
// K2a: conv2 (8->16, 3x3, s2, p1), one frame per block, 1000 blocks.
// Frame in zero-padded LDS [8][34][36]. Wave w -> c_out 4w..4w+3; lane ->
// 4 horizontally-adjacent outputs. Weights via readfirstlane -> s_load.
// ws1: [1000,8,32,32]  w2: [16,8,3,3] -> u2: [1000,16,16,16]
// ============================================================================
#define K2_CIS 1224             // 34 rows * 36 stride

__global__ __launch_bounds__(256) void k2a_conv2(
        const float* __restrict__ ws1, const float* __restrict__ w2,
        float* __restrict__ u2) {
    __shared__ float F[8 * K2_CIS];     // 39,168 B
    const int n = blockIdx.x;
    const int tid = threadIdx.x;

    for (int i = tid; i < 8 * K2_CIS; i += 256) F[i] = 0.f;
    __syncthreads();
    const float4* src = (const float4*)(ws1 + (size_t)n * 8192);
    #pragma unroll
    for (int k = 0; k < 8; k++) {
        const int i = tid + 256 * k;    // 0..2047
        const float4 q = src[i];
        const int ci = i >> 8;
        const int rr = i & 255;
        const int r = rr >> 3, c4 = rr & 7;
        float* d = &F[ci * K2_CIS + (r + 1) * 36 + 1 + 4 * c4];
        d[0] = q.x; d[1] = q.y; d[2] = q.z; d[3] = q.w;
    }
    __syncthreads();

    const int wv = tid >> 6;            // wave id -> c_out 4wv..4wv+3
    const int ln = tid & 63;
    const int oy = ln >> 2;             // 0..15
    const int ox4 = ln & 3;             // 4 outputs at ox = 4*ox4 + 0..3

    float acc[4][4];
    #pragma unroll
    for (int j = 0; j < 4; j++)
        #pragma unroll
        for (int k = 0; k < 4; k++) acc[j][k] = 0.f;

    #pragma unroll
    for (int ci = 0; ci < 8; ci++) {
        float q[3][9];
        const int base = ci * K2_CIS + (2 * oy) * 36 + 8 * ox4;
        #pragma unroll
        for (int ky = 0; ky < 3; ky++) {
            const float4 qa = *(const float4*)&F[base + ky * 36];
            const float4 qb = *(const float4*)&F[base + ky * 36 + 4];
            q[ky][0] = qa.x; q[ky][1] = qa.y; q[ky][2] = qa.z; q[ky][3] = qa.w;
            q[ky][4] = qb.x; q[ky][5] = qb.y; q[ky][6] = qb.z; q[ky][7] = qb.w;
            q[ky][8] = F[base + ky * 36 + 8];
        }
        #pragma unroll
        for (int j = 0; j < 4; j++) {
            const int co_u = __builtin_amdgcn_readfirstlane(4 * wv + j);
            const float* wb = w2 + co_u * 72 + ci * 9;  // uniform -> s_load
            float wm[9];
            #pragma unroll
            for (int m = 0; m < 9; m++) wm[m] = wb[m];
            #pragma unroll
            for (int k = 0; k < 4; k++)
                #pragma unroll
                for (int ky = 0; ky < 3; ky++)
                    #pragma unroll
                    for (int kx = 0; kx < 3; kx++)
                        acc[j][k] += q[ky][2 * k + kx] * wm[ky * 3 + kx];
        }
    }
    float* db = u2 + (size_t)n * 4096 + oy * 16 + 4 * ox4;
    #pragma unroll
    for (int j = 0; j < 4; j++) {
        const int co = 4 * wv + j;
        *(float4*)(db + co * 256) =
            make_float4(acc[j][0], acc[j][1], acc[j][2], acc[j][3]);
    }
}

// ============================================================================
// K2b: IAF scan over T + 2x2 avgpool, stage 2.
// R5 post-mortem: 400 single-wave blocks = 0.39 waves/SIMD, latency fully
// exposed. NEW: 1 thread per IAF state -> 400 blocks x 256 threads
// (1600 waves = 1.56/SIMD, 4x TLP). Block = (b,c); thread (ty,tx) owns one
// pre-pool state; loads are 1 KB/plane fully coalesced; 2x2 pool via two
// shfl_down (x+1 = lane+1, y+1 = lane+16, both in-wave); spike sums are
// 0/1-exact so reassociation is bit-exact. Batch-8 double-buffered regs.
// u2: [1000,16,16,16] -> ws2: [1000,16,8,8]
// ============================================================================
__global__ __launch_bounds__(256) void k2b_scan(
        const float* __restrict__ u2, float* __restrict__ ws2) {
    const int blk = blockIdx.x;         // 0..399
    const int b = blk >> 4;             // batch 0..24
    const int c = blk & 15;             // channel
    const int tid = threadIdx.x;        // ty = tid>>4, tx = tid&15
    const int ty = tid >> 4, tx = tid & 15;
    const bool red = ((ty & 1) == 0) && ((tx & 1) == 0);
    const int po = (ty >> 1) * 8 + (tx >> 1);
    const float* base = u2 + (size_t)(b * 40) * 4096 + c * 256 + tid;
    float* ob = ws2 + (size_t)(b * 40) * 1024 + c * 64 + po;

    float v = 0.f;
    float P[2][8];
    #pragma unroll
    for (int tt = 0; tt < 8; tt++)
        P[0][tt] = base[(size_t)tt * 4096];
    #pragma unroll
    for (int bt = 0; bt < 5; bt++) {
        if (bt < 4) {
            #pragma unroll
            for (int tt = 0; tt < 8; tt++)
                P[(bt + 1) & 1][tt] = base[(size_t)(8 * (bt + 1) + tt) * 4096];
        }
        #pragma unroll
        for (int tt = 0; tt < 8; tt++) {
            const float s = iaf_step(v, P[bt & 1][tt]);
            float r = s + __shfl_down(s, 1);     // + x neighbor
            r += __shfl_down(r, 16);             // + y-row pair
            if (red)
                ob[(size_t)(8 * bt + tt) * 1024] = r * 0.25f;
        }
    }
}

// ============================================================================
// K3: fc1  ws2:[1000,1024] @ w3[64,1024]^T -> ws3:[1000,64]
// 2 rows per block, 500 blocks (w3 served from L2/L3).
// ============================================================================
__global__ __launch_bounds__(256) void k3_fc1(
        const float* __restrict__ ws2, const float* __restrict__ w3,
        float* __restrict__ ws3) {
    __shared__ float rows[2048];
    const int n0 = blockIdx.x * 2;
    const int tid = threadIdx.x;
    const float4* s = (const float4*)(ws2 + (size_t)n0 * 1024);
    #pragma unroll
    for (int k = 0; k < 2; k++)
        ((float4*)rows)[tid + 256 * k] = s[tid + 256 * k];
    __syncthreads();
    const int o = tid >> 2, ko = tid & 3;
    const float4* wp = (const float4*)(w3 + (size_t)o * 1024 + ko * 256);
    const float4* r0 = (const float4*)(rows + ko * 256);
    const float4* r1 = (const float4*)(rows + 1024 + ko * 256);
    float a0 = 0.f, a1 = 0.f;
    #pragma unroll 8
    for (int j = 0; j < 64; j++) {
        const float4 wv = wp[j];
        const float4 q0 = r0[j], q1 = r1[j];
        a0 += q0.x * wv.x + q0.y * wv.y + q0.z * wv.z + q0.w * wv.w;
        a1 += q1.x * wv.x + q1.y * wv.y + q1.z * wv.z + q1.w * wv.w;
    }
    a0 += __shfl_xor(a0, 1); a0 += __shfl_xor(a0, 2);
    a1 += __shfl_xor(a1, 1); a1 += __shfl_xor(a1, 2);
    if (ko == 0) {
        ws3[(size_t)(n0 + 0) * 64 + o] = a0;
        ws3[(size_t)(n0 + 1) * 64 + o] = a1;
    }
}

// ============================================================================
// K4: IAF + fc2 (64->11) + IAF. 256-thread blocks: parallel stage of all
// 2560 inputs + w4, wave-0 runs the 40-step IAF1 scan wholly in LDS,
// phase B (440 dots) and phase C in parallel.
// ============================================================================
__global__ __launch_bounds__(256) void k4_iaf_fc2_iaf(
        const float* __restrict__ ws3, const float* __restrict__ w4,
        float* __restrict__ out) {
    __shared__ float sld[2560];
    __shared__ float pre[40 * 12];
    __shared__ float w4s[704];
    const int b = blockIdx.x, tid = threadIdx.x;

    const float4* src = (const float4*)(ws3 + (size_t)b * 2560);
    for (int i = tid; i < 640; i += 256) ((float4*)sld)[i] = src[i];
    for (int i = tid; i < 176; i += 256) ((float4*)w4s)[i] = ((const float4*)w4)[i];
    __syncthreads();
    if (tid < 64) {                     // wave 0: IAF1 scan in place
        float v1 = 0.f;
        #pragma unroll
        for (int t = 0; t < 40; t++)
            sld[t * 64 + tid] = iaf_step(v1, sld[t * 64 + tid]);
    }
    __syncthreads();
    for (int idx = tid; idx < 440; idx += 256) {
        const int t = idx % 40, o = idx / 40;
        const float4* spr = (const float4*)(sld + t * 64);
        const float4* wr = (const float4*)(w4s + o * 64);
        float acc = 0.f;
        #pragma unroll
        for (int qq = 0; qq < 16; qq++) {
            const float4 a = spr[qq], ww = wr[qq];
            acc += a.x * ww.x + a.y * ww.y + a.z * ww.z + a.w * ww.w;
        }
        pre[t * 12 + o] = acc;
    }
    __syncthreads();
    if (tid < 11) {
        float v2 = 0.f;
        for (int t = 0; t < 40; t++)
            out[(size_t)(b * 40 + t) * 11 + tid] = iaf_step(v2, pre[t * 12 + tid]);
    }
}

extern "C" void kernel_launch(void* const* d_in, const int* in_sizes, int n_in,
                              void* d_out, int out_size, void* d_ws, size_t ws_size,
                              hipStream_t stream) {
    const float* x  = (const float*)d_in[0];   // [25,40,2,128,128]
    const float* w1 = (const float*)d_in[1];   // [8,2,3,3]
    const float* w2 = (const float*)d_in[2];   // [16,8,3,3]
    const float* w3 = (const float*)d_in[3];   // [64,1024]
    const float* w4 = (const float*)d_in[4];   // [11,64]
    float* out = (float*)d_out;                // [25,40,11]

    float* ws1 = (float*)d_ws;                 // 1000*8*32*32 = 8,192,000 f
    float* ws2 = ws1 + 8192000;                // 1000*16*8*8  = 1,024,000 f
    float* ws3 = ws2 + 1024000;                // 1000*64      =    64,000 f
    // u2 (16.4 MB): prefer d_ws (keeps inputs pristine); fall back to x's
    // buffer (x dead after K1) only if the workspace is too small.
    float* u2;
    if (ws_size >= (size_t)(8192000 + 1024000 + 64000 + 4096000) * 4)
        u2 = ws3 + 64000;
    else
        u2 = (float*)d_in[0];

    k1_conv1_iaf_pool<<<3200, 64, 0, stream>>>(x, w1, ws1);
    k2a_conv2<<<1000, 256, 0, stream>>>(ws1, w2, u2);
    k2b_scan<<<400, 256, 0, stream>>>(u2, ws2);
    k3_fc1<<<500, 256, 0, stream>>>(ws2, w3, ws3);
    k4_iaf_fc2_iaf<<<25, 256, 0, stream>>>(ws3, w4, out);
}